// Round 13
// baseline (84.323 us; speedup 1.0000x reference)
//
#include <hip/hip_runtime.h>
#include <math.h>

// x:      [4,1024,768] fp32 -> bf16 (prep)
// w_qkv:  [768,2304]   fp32 -> bf16 transposed [2304,768] (prep)
// w_out:  [768,768]    fp32 -> bf16 transposed [768,768]  (prep)
// b_out:  [768]        fp32
// out:    [4,1024,768] fp32
// HEADS=12, DH=64.  Q pre-scaled by 0.125*log2(e) -> softmax in exp2 domain.
//
// Q/K/V in MFMA-fragment-order global layouts (attn loads = base + lane*16B):
//   Qf,Kf: [bh][blk32][kt(4)][hi(2)][r(32)][j(8)]
//   Vf:    [bh][blk64][ks(4)][hi(2)][d(64)][j(8)]
//
// GEMMs: 64x128 tile, reg-staged global->reg->LDS, depth-3 pipeline, 2 LDS
// buffers, fully unrolled K-loop, one raw barrier per step.
// gemm_qkv XCD swizzle sized so per-XCD working set (A 1.57MB + B 1.76MB)
// fits the 4MB L2 (R12's swizzle had B thrashing: 4.15MB).

typedef __attribute__((ext_vector_type(8))) __bf16 bf16x8;
typedef __attribute__((ext_vector_type(4))) float f32x4;
typedef __attribute__((ext_vector_type(16))) float f32x16;
typedef unsigned short u16;
typedef unsigned int u32;

#define ZERO16 {0,0,0,0,0,0,0,0,0,0,0,0,0,0,0,0}

__device__ __forceinline__ u16 f2bf(float f) {
    union { float f; unsigned u; } v; v.f = f;
    unsigned r = v.u + 0x7FFF + ((v.u >> 16) & 1);   // RNE
    return (u16)(r >> 16);
}

__device__ __forceinline__ u32 cvtpk(float lo, float hi) {
    u32 r;
    asm("v_cvt_pk_bf16_f32 %0, %1, %2" : "=v"(r) : "v"(lo), "v"(hi));
    return r;
}
__device__ __forceinline__ float xhalf_max(float x) {
    float o = __shfl_xor(x, 32);
    return fmaxf(x, o);
}
__device__ __forceinline__ float xhalf_sum(float x) {
    float o = __shfl_xor(x, 32);
    return x + o;
}

// ---------------------------------------------------------------------------
// Fused prep: convert x -> bf16 (blocks 0..3071), transpose+convert w_qkv
// (3072..4799), transpose+convert w_out (4800..5375).
// ---------------------------------------------------------------------------
__global__ __launch_bounds__(256) void prep(const float* __restrict__ x,
                                            const float* __restrict__ w_qkv,
                                            const float* __restrict__ w_out,
                                            u16* __restrict__ xb,
                                            u16* __restrict__ wqkvT,
                                            u16* __restrict__ woutT) {
    __shared__ float T[32][33];
    const int bid = blockIdx.x;
    if (bid < 3072) {
        int i = bid * 256 + threadIdx.x;
        float4 v = reinterpret_cast<const float4*>(x)[i];
        union { u16 s[4]; int2 p; } o;
        o.s[0] = f2bf(v.x); o.s[1] = f2bf(v.y); o.s[2] = f2bf(v.z); o.s[3] = f2bf(v.w);
        reinterpret_cast<int2*>(xb)[i] = o.p;
        return;
    }
    const float* in;
    u16* out;
    int R, C, c0, r0;
    if (bid < 4800) {
        int r = bid - 3072;
        in = w_qkv; out = wqkvT; R = 768; C = 2304;
        c0 = (r % 72) * 32; r0 = (r / 72) * 32;
    } else {
        int r = bid - 4800;
        in = w_out; out = woutT; R = 768; C = 768;
        c0 = (r % 24) * 32; r0 = (r / 24) * 32;
    }
    const int tx = threadIdx.x & 31;
    const int ty = threadIdx.x >> 5;
#pragma unroll
    for (int p = 0; p < 4; ++p) {
        int ry = ty + p * 8;
        T[ry][tx] = in[(size_t)(r0 + ry) * C + c0 + tx];
    }
    __syncthreads();
#pragma unroll
    for (int p = 0; p < 4; ++p) {
        int cy = ty + p * 8;
        out[(size_t)(c0 + cy) * R + r0 + tx] = f2bf(T[tx][cy]);
    }
}

// ---------------------------------------------------------------------------
// GEMM1: qkv = x_bf16 @ w_qkv (via wqkvT); scatter into fragment-order
// Qf (scaled), Kf, Vf.  64x128 tile, depth-3 reg-staged pipeline.
// ---------------------------------------------------------------------------
__global__ __launch_bounds__(256) void gemm_qkv(const u16* __restrict__ A,
                                                const u16* __restrict__ BT,
                                                u16* __restrict__ Qf,
                                                u16* __restrict__ Kf,
                                                u16* __restrict__ Vf) {
    __shared__ u16 As[2][64 * 32];
    __shared__ u16 Bs[2][128 * 32];
    const int tid = threadIdx.x;
    const int lane = tid & 63;
    const int w = tid >> 6;
    const int wm = w >> 1, wn = w & 1;       // wave = 32x64 of the 64x128 tile
    const int lr = lane & 15;
    const int lk = lane >> 4;
    // L2-sized XCD swizzle: each XCD = 16 row-panels x 9 col-panels
    // (A 1.57MB + B 1.76MB = 3.33MB < 4MB).  16 consecutive local blocks
    // share one B col panel (col-major within XCD).
    const int xcd = blockIdx.x & 7;
    const int lid = blockIdx.x >> 3;         // 0..143
    const int row0 = ((xcd & 3) * 16 + (lid & 15)) * 64;
    const int col0 = ((xcd >> 2) * 9 + (lid >> 4)) * 128;
    const int sr = lane >> 2;      // staging row (16 per wave)
    const int scg = lane & 3;      // staging 16B col group

    f32x4 acc[2][4];
#pragma unroll
    for (int mi = 0; mi < 2; ++mi)
#pragma unroll
        for (int nj = 0; nj < 4; ++nj) acc[mi][nj] = (f32x4){0.f, 0.f, 0.f, 0.f};

    const u16* aSrc = A  + (size_t)(row0 + w * 16 + sr) * 768 + scg * 8;
    const u16* bSrc0 = BT + (size_t)(col0 + w * 16 + sr) * 768 + scg * 8;
    const u16* bSrc1 = BT + (size_t)(col0 + (4 + w) * 16 + sr) * 768 + scg * 8;
    u16* aDst = &As[0][(w * 16 + sr) * 32 + scg * 8];
    u16* bDst0 = &Bs[0][(w * 16 + sr) * 32 + scg * 8];
    u16* bDst1 = &Bs[0][((4 + w) * 16 + sr) * 32 + scg * 8];

    int4 sa[3], sb0[3], sb1[3];    // 3 staging reg-sets (static rotation)

#define LOADR(S, K0)                                                    \
    sa[S]  = *reinterpret_cast<const int4*>(aSrc  + (K0));              \
    sb0[S] = *reinterpret_cast<const int4*>(bSrc0 + (K0));              \
    sb1[S] = *reinterpret_cast<const int4*>(bSrc1 + (K0));
#define WRITER(BUF, S)                                                  \
    *reinterpret_cast<int4*>(aDst  + (BUF) * 64 * 32)  = sa[S];         \
    *reinterpret_cast<int4*>(bDst0 + (BUF) * 128 * 32) = sb0[S];        \
    *reinterpret_cast<int4*>(bDst1 + (BUF) * 128 * 32) = sb1[S];
#define COMPUTE(BUF)                                                          \
    {                                                                         \
        bf16x8 af[2], bfr[4];                                                 \
        _Pragma("unroll")                                                     \
        for (int mi = 0; mi < 2; ++mi)                                        \
            af[mi] = *reinterpret_cast<const bf16x8*>(&As[BUF][(wm * 32 + mi * 16 + lr) * 32 + lk * 8]); \
        _Pragma("unroll")                                                     \
        for (int nj = 0; nj < 4; ++nj)                                        \
            bfr[nj] = *reinterpret_cast<const bf16x8*>(&Bs[BUF][(wn * 64 + nj * 16 + lr) * 32 + lk * 8]); \
        __builtin_amdgcn_s_setprio(1);                                        \
        _Pragma("unroll")                                                     \
        for (int mi = 0; mi < 2; ++mi)                                        \
            _Pragma("unroll")                                                 \
            for (int nj = 0; nj < 4; ++nj)                                    \
                acc[mi][nj] = __builtin_amdgcn_mfma_f32_16x16x32_bf16(af[mi], bfr[nj], acc[mi][nj], 0, 0, 0); \
        __builtin_amdgcn_s_setprio(0);                                        \
    }
#define BARRIER()                                                       \
    asm volatile("s_waitcnt lgkmcnt(0)" ::: "memory");                  \
    __builtin_amdgcn_sched_barrier(0);                                  \
    __builtin_amdgcn_s_barrier();

    // prologue: sets 0,1,2 <- tiles 0,1,2; buf0 <- tile 0
    LOADR(0, 0);
    LOADR(1, 32);
    LOADR(2, 64);
    WRITER(0, 0);
    BARRIER();

#pragma unroll
    for (int t = 0; t < 24; ++t) {
        if (t + 3 < 24) { LOADR(t % 3, (t + 3) * 32); }       // issue tile t+3
        COMPUTE(t & 1);                                        // consume tile t
        if (t + 1 < 24) { WRITER((t + 1) & 1, (t + 1) % 3); }  // LDS <- tile t+1
        if (t + 1 < 24) { BARRIER(); }
    }
#undef LOADR
#undef WRITER
#undef COMPUTE
#undef BARRIER

    const int which = col0 / 768;
    const int cb = col0 - which * 768;
#pragma unroll
    for (int mi = 0; mi < 2; ++mi) {
#pragma unroll
        for (int i = 0; i < 4; ++i) {
            int r = row0 + wm * 32 + mi * 16 + lk * 4 + i;
            int b = r >> 10, n = r & 1023;
#pragma unroll
            for (int nj = 0; nj < 4; ++nj) {
                int cw = cb + wn * 64 + nj * 16 + lr;
                int h = cw >> 6, d = cw & 63;
                int bh = b * 12 + h;
                float val = acc[mi][nj][i];
                if (which == 2) {
                    size_t off = ((((size_t)bh * 16 + (n >> 6)) * 4 + ((n >> 4) & 3)) * 2 + ((n >> 3) & 1)) * 512
                                 + d * 8 + (n & 7);
                    Vf[off] = f2bf(val);
                } else {
                    size_t off = ((((size_t)bh * 32 + (n >> 5)) * 4 + (d >> 4)) * 2 + ((d >> 3) & 1)) * 256
                                 + (n & 31) * 8 + (d & 7);
                    if (which == 0) Qf[off] = f2bf(val * 0.18033688f);   // 0.125*log2(e)
                    else            Kf[off] = f2bf(val);
                }
            }
        }
    }
}

// ---------------------------------------------------------------------------
// Flash attention, swapped-operand 32x32x16 MFMA, fragment-order global
// layouts -> every load is base + lane*16B.  No LDS / barriers in KV loop.
// ---------------------------------------------------------------------------
#define GETO(dt, r) ((dt) == 0 ? o0[r] : o1[r])

__global__ __launch_bounds__(256) void attn_mfma(const u16* __restrict__ Qf,
                                                 const u16* __restrict__ Kf,
                                                 const u16* __restrict__ Vf,
                                                 u16* __restrict__ attn_out) {
    __shared__ float OtM[2][64][33];
    __shared__ float Lm[2][32], Ll[2][32];
    __shared__ u16 Os[2][32][72];

    const int tid = threadIdx.x;
    const int lane = tid & 63;
    const int w = tid >> 6;
    const int qsub = w & 1;
    const int half = w >> 1;
    const int l31 = lane & 31;
    const int hi = lane >> 5;

    const int bid = blockIdx.x;
    const int lin = (bid & 7) * 96 + (bid >> 3);
    const int qt = lin & 15;
    const int bh = lin >> 4;

    const u16* Qh = Qf + (size_t)bh * 65536;
    const u16* Kh = Kf + (size_t)bh * 65536;
    const u16* Vh = Vf + (size_t)bh * 65536;

    bf16x8 qf[4];
#pragma unroll
    for (int kt = 0; kt < 4; ++kt)
        qf[kt] = *reinterpret_cast<const bf16x8*>(
            Qh + (((size_t)(qt * 2 + qsub) * 4 + kt) * 2 + hi) * 256 + l31 * 8);

    f32x16 o0 = ZERO16, o1 = ZERO16;
    float m = -1e30f, l = 0.f;

    for (int it = 0; it < 8; ++it) {
        const int kb0 = it * 4 + half * 2;
        const int kvb = it * 2 + half;

        bf16x8 kf0[4], kf1[4];
#pragma unroll
        for (int kt = 0; kt < 4; ++kt) {
            kf0[kt] = *reinterpret_cast<const bf16x8*>(
                Kh + (((size_t)kb0 * 4 + kt) * 2 + hi) * 256 + l31 * 8);
            kf1[kt] = *reinterpret_cast<const bf16x8*>(
                Kh + (((size_t)(kb0 + 1) * 4 + kt) * 2 + hi) * 256 + l31 * 8);
        }
        bf16x8 vf0[4], vf1[4];
#pragma unroll
        for (int ks = 0; ks < 4; ++ks) {
            const u16* vb = Vh + (((size_t)kvb * 4 + ks) * 2 + hi) * 512;
            vf0[ks] = *reinterpret_cast<const bf16x8*>(vb + l31 * 8);
            vf1[ks] = *reinterpret_cast<const bf16x8*>(vb + (l31 + 32) * 8);
        }

        f32x16 s0 = ZERO16, s1 = ZERO16;
        __builtin_amdgcn_s_setprio(1);
#pragma unroll
        for (int kt = 0; kt < 4; ++kt) s0 = __builtin_amdgcn_mfma_f32_32x32x16_bf16(kf0[kt], qf[kt], s0, 0, 0, 0);
#pragma unroll
        for (int kt = 0; kt < 4; ++kt) s1 = __builtin_amdgcn_mfma_f32_32x32x16_bf16(kf1[kt], qf[kt], s1, 0, 0, 0);
        __builtin_amdgcn_s_setprio(0);

        float mx[8];
#pragma unroll
        for (int i = 0; i < 8; ++i)
            mx[i] = fmaxf(fmaxf(s0[2*i], s0[2*i+1]), fmaxf(s1[2*i], s1[2*i+1]));
        float pmax = fmaxf(fmaxf(fmaxf(mx[0], mx[1]), fmaxf(mx[2], mx[3])),
                           fmaxf(fmaxf(mx[4], mx[5]), fmaxf(mx[6], mx[7])));
        pmax = xhalf_max(pmax);

        if (!__all(pmax <= m + 8.f)) {
            float mn = fmaxf(m, pmax);
            float c = __builtin_amdgcn_exp2f(m - mn);
            m = mn; l *= c;
            o0 = o0 * c; o1 = o1 * c;
        }

#pragma unroll
        for (int r = 0; r < 16; ++r) s0[r] = __builtin_amdgcn_exp2f(s0[r] - m);
#pragma unroll
        for (int r = 0; r < 16; ++r) s1[r] = __builtin_amdgcn_exp2f(s1[r] - m);
        float sm[8];
#pragma unroll
        for (int i = 0; i < 8; ++i)
            sm[i] = (s0[2*i] + s0[2*i+1]) + (s1[2*i] + s1[2*i+1]);
        float tsum = ((sm[0]+sm[1]) + (sm[2]+sm[3])) + ((sm[4]+sm[5]) + (sm[6]+sm[7]));
        l += xhalf_sum(tsum);

        bf16x8 pb[4];
#define PACK_GROUP(S, G, OUT)                                           \
        {                                                               \
            u32 X0 = cvtpk(S[8*(G)+0], S[8*(G)+1]);                     \
            u32 X1 = cvtpk(S[8*(G)+2], S[8*(G)+3]);                     \
            u32 Y0 = cvtpk(S[8*(G)+4], S[8*(G)+5]);                     \
            u32 Y1 = cvtpk(S[8*(G)+6], S[8*(G)+7]);                     \
            u32 X0s = (u32)__shfl_xor((int)X0, 32);                     \
            u32 X1s = (u32)__shfl_xor((int)X1, 32);                     \
            u32 Y0s = (u32)__shfl_xor((int)Y0, 32);                     \
            u32 Y1s = (u32)__shfl_xor((int)Y1, 32);                     \
            union { u32 u[4]; bf16x8 v; } pk_;                          \
            pk_.u[0] = hi ? Y0s : X0;                                   \
            pk_.u[1] = hi ? Y1s : X1;                                   \
            pk_.u[2] = hi ? Y0 : X0s;                                   \
            pk_.u[3] = hi ? Y1 : X1s;                                   \
            OUT = pk_.v;                                                \
        }
        PACK_GROUP(s0, 0, pb[0]);
        PACK_GROUP(s0, 1, pb[1]);
        PACK_GROUP(s1, 0, pb[2]);
        PACK_GROUP(s1, 1, pb[3]);
#undef PACK_GROUP

        __builtin_amdgcn_s_setprio(1);
#pragma unroll
        for (int ks = 0; ks < 4; ++ks) {
            o0 = __builtin_amdgcn_mfma_f32_32x32x16_bf16(vf0[ks], pb[ks], o0, 0, 0, 0);
            o1 = __builtin_amdgcn_mfma_f32_32x32x16_bf16(vf1[ks], pb[ks], o1, 0, 0, 0);
        }
        __builtin_amdgcn_s_setprio(0);
    }

    if (half == 1) {
#pragma unroll
        for (int dt = 0; dt < 2; ++dt)
#pragma unroll
            for (int r = 0; r < 16; ++r)
                OtM[qsub][dt * 32 + (r & 3) + 8 * (r >> 2) + 4 * hi][l31] = GETO(dt, r);
        Lm[qsub][l31] = m;
        Ll[qsub][l31] = l;
    }
    __syncthreads();
    if (half == 0) {
        float m2 = Lm[qsub][l31], l2 = Ll[qsub][l31];
        float mn = fmaxf(m, m2);
        float a = __builtin_amdgcn_exp2f(m - mn);
        float bsc = __builtin_amdgcn_exp2f(m2 - mn);
        float lm = l * a + l2 * bsc;
        float inv = 1.0f / lm;
        float av = a * inv, bv = bsc * inv;
#pragma unroll
        for (int dt = 0; dt < 2; ++dt)
#pragma unroll
            for (int rq = 0; rq < 4; ++rq) {
                int d0 = dt * 32 + 8 * rq + 4 * hi;
                float v0 = GETO(dt, rq * 4 + 0) * av + OtM[qsub][d0 + 0][l31] * bv;
                float v1 = GETO(dt, rq * 4 + 1) * av + OtM[qsub][d0 + 1][l31] * bv;
                float v2 = GETO(dt, rq * 4 + 2) * av + OtM[qsub][d0 + 2][l31] * bv;
                float v3 = GETO(dt, rq * 4 + 3) * av + OtM[qsub][d0 + 3][l31] * bv;
                uint2 pr;
                pr.x = cvtpk(v0, v1);
                pr.y = cvtpk(v2, v3);
                *reinterpret_cast<uint2*>(&Os[qsub][l31][d0]) = pr;
            }
    }
    __syncthreads();

    const int b = bh / 12, h = bh % 12;
#pragma unroll
    for (int it2 = 0; it2 < 2; ++it2) {
        int idx = tid + it2 * 256;
        int token = idx >> 3;
        int chunk = idx & 7;
        int4 v = *reinterpret_cast<const int4*>(&Os[token >> 5][token & 31][chunk * 8]);
        *reinterpret_cast<int4*>(&attn_out[((size_t)(b * 1024 + qt * 64 + token)) * 768 + h * 64 + chunk * 8]) = v;
    }
}

// ---------------------------------------------------------------------------
// GEMM2: out = attn_bf16 @ w_out (via woutT) + b_out.  64x128 tile,
// depth-3 reg-staged pipeline.
// ---------------------------------------------------------------------------
__global__ __launch_bounds__(256) void gemm_out(const u16* __restrict__ A,
                                                const u16* __restrict__ BT,
                                                const float* __restrict__ bias,
                                                float* __restrict__ out) {
    __shared__ u16 As[2][64 * 32];
    __shared__ u16 Bs[2][128 * 32];
    const int tid = threadIdx.x;
    const int lane = tid & 63;
    const int w = tid >> 6;
    const int wm = w >> 1, wn = w & 1;
    const int lr = lane & 15;
    const int lk = lane >> 4;
    // XCD swizzle: 48/XCD = 6 cols x 8 rows (B 1.1MB total -> already L2-fits)
    const int orig = blockIdx.x >> 3;
    const int xcd = blockIdx.x & 7;
    const int col0 = (orig >> 3) * 128;                 // 0..5
    const int row0 = (xcd * 8 + (orig & 7)) * 64;
    const int sr = lane >> 2;
    const int scg = lane & 3;

    f32x4 acc[2][4];
#pragma unroll
    for (int mi = 0; mi < 2; ++mi)
#pragma unroll
        for (int nj = 0; nj < 4; ++nj) acc[mi][nj] = (f32x4){0.f, 0.f, 0.f, 0.f};

    const u16* aSrc = A  + (size_t)(row0 + w * 16 + sr) * 768 + scg * 8;
    const u16* bSrc0 = BT + (size_t)(col0 + w * 16 + sr) * 768 + scg * 8;
    const u16* bSrc1 = BT + (size_t)(col0 + (4 + w) * 16 + sr) * 768 + scg * 8;
    u16* aDst = &As[0][(w * 16 + sr) * 32 + scg * 8];
    u16* bDst0 = &Bs[0][(w * 16 + sr) * 32 + scg * 8];
    u16* bDst1 = &Bs[0][((4 + w) * 16 + sr) * 32 + scg * 8];

    int4 sa[3], sb0[3], sb1[3];

#define LOADR(S, K0)                                                    \
    sa[S]  = *reinterpret_cast<const int4*>(aSrc  + (K0));              \
    sb0[S] = *reinterpret_cast<const int4*>(bSrc0 + (K0));              \
    sb1[S] = *reinterpret_cast<const int4*>(bSrc1 + (K0));
#define WRITER(BUF, S)                                                  \
    *reinterpret_cast<int4*>(aDst  + (BUF) * 64 * 32)  = sa[S];         \
    *reinterpret_cast<int4*>(bDst0 + (BUF) * 128 * 32) = sb0[S];        \
    *reinterpret_cast<int4*>(bDst1 + (BUF) * 128 * 32) = sb1[S];
#define COMPUTE(BUF)                                                          \
    {                                                                         \
        bf16x8 af[2], bfr[4];                                                 \
        _Pragma("unroll")                                                     \
        for (int mi = 0; mi < 2; ++mi)                                        \
            af[mi] = *reinterpret_cast<const bf16x8*>(&As[BUF][(wm * 32 + mi * 16 + lr) * 32 + lk * 8]); \
        _Pragma("unroll")                                                     \
        for (int nj = 0; nj < 4; ++nj)                                        \
            bfr[nj] = *reinterpret_cast<const bf16x8*>(&Bs[BUF][(wn * 64 + nj * 16 + lr) * 32 + lk * 8]); \
        __builtin_amdgcn_s_setprio(1);                                        \
        _Pragma("unroll")                                                     \
        for (int mi = 0; mi < 2; ++mi)                                        \
            _Pragma("unroll")                                                 \
            for (int nj = 0; nj < 4; ++nj)                                    \
                acc[mi][nj] = __builtin_amdgcn_mfma_f32_16x16x32_bf16(af[mi], bfr[nj], acc[mi][nj], 0, 0, 0); \
        __builtin_amdgcn_s_setprio(0);                                        \
    }
#define BARRIER()                                                       \
    asm volatile("s_waitcnt lgkmcnt(0)" ::: "memory");                  \
    __builtin_amdgcn_sched_barrier(0);                                  \
    __builtin_amdgcn_s_barrier();

    LOADR(0, 0);
    LOADR(1, 32);
    LOADR(2, 64);
    WRITER(0, 0);
    BARRIER();

#pragma unroll
    for (int t = 0; t < 24; ++t) {
        if (t + 3 < 24) { LOADR(t % 3, (t + 3) * 32); }
        COMPUTE(t & 1);
        if (t + 1 < 24) { WRITER((t + 1) & 1, (t + 1) % 3); }
        if (t + 1 < 24) { BARRIER(); }
    }
#undef LOADR
#undef WRITER
#undef COMPUTE
#undef BARRIER

#pragma unroll
    for (int mi = 0; mi < 2; ++mi)
#pragma unroll
        for (int i = 0; i < 4; ++i) {
            int r = row0 + wm * 32 + mi * 16 + lk * 4 + i;
#pragma unroll
            for (int nj = 0; nj < 4; ++nj) {
                int c = col0 + wn * 64 + nj * 16 + lr;
                out[(size_t)r * 768 + c] = acc[mi][nj][i] + bias[c];
            }
        }
}

// ---------------------------------------------------------------------------
extern "C" void kernel_launch(void* const* d_in, const int* in_sizes, int n_in,
                              void* d_out, int out_size, void* d_ws, size_t ws_size,
                              hipStream_t stream) {
    const float* x     = (const float*)d_in[0];
    const float* w_qkv = (const float*)d_in[1];
    const float* w_out = (const float*)d_in[2];
    const float* b_out = (const float*)d_in[3];
    float* out = (float*)d_out;

    u16* ws = (u16*)d_ws;
    const size_t n_x = (size_t)4096 * 768;
    u16* xb     = ws;
    u16* wqkvT  = xb + n_x;
    u16* woutT  = wqkvT + (size_t)2304 * 768;
    u16* Qfr    = woutT + (size_t)768 * 768;      // fragment-order, 65536/bh
    u16* Kfr    = Qfr + n_x;
    u16* Vfr    = Kfr + n_x;
    u16* attnb  = Vfr + n_x;

    prep<<<5376, 256, 0, stream>>>(x, w_qkv, w_out, xb, wqkvT, woutT);
    gemm_qkv<<<1152, 256, 0, stream>>>(xb, wqkvT, Qfr, Kfr, Vfr);
    attn_mfma<<<768, 256, 0, stream>>>(Qfr, Kfr, Vfr, attnb);
    gemm_out<<<384, 256, 0, stream>>>(attnb, woutT, b_out, out);
}

// Round 14
// 78.953 us; speedup vs baseline: 1.0680x; 1.0680x over previous
//
#include <hip/hip_runtime.h>
#include <math.h>

// All GEMM operands stored in MFMA-FRAGMENT-ORDER (zero-LDS zero-barrier
// GEMMs, the structure that made attn_mfma fast):
//   fragoff(m,k): element (m,k) of a [M][768] matrix lives at
//   ((m>>4)*24 + (k>>5))*512 + ((m&15) + 16*((k&31)>>3))*8 + (k&7)
//   -> each 16x32 fragment is 1KB, lane l's 8 elems contiguous at l*8.
// Q/K/V keep the R6 fragment-order layouts (attn unchanged).
// HEADS=12, DH=64.  Q pre-scaled by 0.125*log2(e) -> softmax in exp2 domain.

typedef __attribute__((ext_vector_type(8))) __bf16 bf16x8;
typedef __attribute__((ext_vector_type(4))) float f32x4;
typedef __attribute__((ext_vector_type(16))) float f32x16;
typedef unsigned short u16;
typedef unsigned int u32;

#define ZERO16 {0,0,0,0,0,0,0,0,0,0,0,0,0,0,0,0}

__device__ __forceinline__ u16 f2bf(float f) {
    union { float f; unsigned u; } v; v.f = f;
    unsigned r = v.u + 0x7FFF + ((v.u >> 16) & 1);   // RNE
    return (u16)(r >> 16);
}

__device__ __forceinline__ u32 cvtpk(float lo, float hi) {
    u32 r;
    asm("v_cvt_pk_bf16_f32 %0, %1, %2" : "=v"(r) : "v"(lo), "v"(hi));
    return r;
}
__device__ __forceinline__ float xhalf_max(float x) {
    float o = __shfl_xor(x, 32);
    return fmaxf(x, o);
}
__device__ __forceinline__ float xhalf_sum(float x) {
    float o = __shfl_xor(x, 32);
    return x + o;
}

// fragment-order offset for a [M][768] row-major logical matrix (K=768)
__device__ __forceinline__ size_t fragoff(int m, int k) {
    return (((size_t)(m >> 4) * 24 + (k >> 5)) * 64 + (m & 15) + 16 * ((k & 31) >> 3)) * 8 + (k & 7);
}

// ---------------------------------------------------------------------------
// prep: blocks 0..1535: x -> xA fragment-order (LDS-tiled 32x64);
//       1536..3263: w_qkv -> wB frag-order [n=2304][k=768];
//       3264..3839: w_out -> wO frag-order [n=768][k=768].
// ---------------------------------------------------------------------------
__global__ __launch_bounds__(256) void prep(const float* __restrict__ x,
                                            const float* __restrict__ w_qkv,
                                            const float* __restrict__ w_out,
                                            u16* __restrict__ xA,
                                            u16* __restrict__ wB,
                                            u16* __restrict__ wO) {
    const int bid = blockIdx.x;
    const int tid = threadIdx.x;
    if (bid < 1536) {
        __shared__ float Tx[32][65];
        const int mt = bid & 127;        // 0..127 (32-row tiles)
        const int kt = bid >> 7;         // 0..11  (64-col tiles)
        const int r0 = mt * 32, k0 = kt * 64;
#pragma unroll
        for (int p = 0; p < 2; ++p) {
            int idx = tid + p * 256;
            int row = idx >> 4, c4 = idx & 15;
            float4 v = *reinterpret_cast<const float4*>(&x[(size_t)(r0 + row) * 768 + k0 + c4 * 4]);
            *reinterpret_cast<float4*>(&Tx[row][c4 * 4]) = v;
        }
        __syncthreads();
        const int f = tid >> 6, l = tid & 63;
        const int fm = f & 1, fk = f >> 1;
        const int lm = l & 15, lkc = l >> 4;
        const int lrow = fm * 16 + lm;
        const int lcol = fk * 32 + lkc * 8;
        float v0 = Tx[lrow][lcol + 0], v1 = Tx[lrow][lcol + 1];
        float v2 = Tx[lrow][lcol + 2], v3 = Tx[lrow][lcol + 3];
        float v4 = Tx[lrow][lcol + 4], v5 = Tx[lrow][lcol + 5];
        float v6 = Tx[lrow][lcol + 6], v7 = Tx[lrow][lcol + 7];
        int4 ov;
        ov.x = (int)cvtpk(v0, v1); ov.y = (int)cvtpk(v2, v3);
        ov.z = (int)cvtpk(v4, v5); ov.w = (int)cvtpk(v6, v7);
        *reinterpret_cast<int4*>(xA + fragoff(r0 + lrow, k0 + lcol)) = ov;
        return;
    }
    // weight transposes: read [k][n] fp32, write frag-order (n, k)
    __shared__ float T[32][33];
    const float* in;
    u16* out;
    int C, c0, r0;
    if (bid < 3264) {
        int r = bid - 1536;
        in = w_qkv; out = wB; C = 2304;
        c0 = (r % 72) * 32; r0 = (r / 72) * 32;
    } else {
        int r = bid - 3264;
        in = w_out; out = wO; C = 768;
        c0 = (r % 24) * 32; r0 = (r / 24) * 32;
    }
    const int tx = tid & 31;
    const int ty = tid >> 5;
#pragma unroll
    for (int p = 0; p < 4; ++p) {
        int ry = ty + p * 8;
        T[ry][tx] = in[(size_t)(r0 + ry) * C + c0 + tx];
    }
    __syncthreads();
#pragma unroll
    for (int p = 0; p < 4; ++p) {
        int cy = ty + p * 8;
        out[fragoff(c0 + cy, r0 + tx)] = f2bf(T[tx][cy]);   // n = c0+cy, k = r0+tx
    }
}

// ---------------------------------------------------------------------------
// GEMM1: qkv = xA @ wB (both fragment-order) -> Qf (scaled), Kf, Vf.
// 128x128 block, 4 waves (64x64 each), ZERO LDS / barriers, depth-3 reg
// prefetch, fully unrolled 24 K-steps.
// ---------------------------------------------------------------------------
__global__ __launch_bounds__(256) void gemm_qkv(const u16* __restrict__ xA,
                                                const u16* __restrict__ wB,
                                                u16* __restrict__ Qf,
                                                u16* __restrict__ Kf,
                                                u16* __restrict__ Vf) {
    const int tid = threadIdx.x;
    const int lane = tid & 63;
    const int w = tid >> 6;
    const int wm = w >> 1, wn = w & 1;
    const int lr = lane & 15;
    const int lk = lane >> 4;
    // XCD swizzle: 576 = 8 x 72; XCD region = 8 row-panels x 9 col-panels
    // (A 1.57MB + B 1.76MB = 3.3MB < 4MB L2)
    const int xcd = blockIdx.x & 7;
    const int lid = blockIdx.x >> 3;                  // 0..71
    const int row0 = ((xcd & 3) * 8 + (lid & 7)) * 128;
    const int col0 = ((xcd >> 2) * 9 + (lid >> 3)) * 128;
    const int R0 = row0 + wm * 64;
    const int C0 = col0 + wn * 64;
    const u16* aB = xA + (size_t)(R0 >> 4) * 24 * 512 + lane * 8;
    const u16* bB = wB + (size_t)(C0 >> 4) * 24 * 512 + lane * 8;

    f32x4 acc[4][4];
#pragma unroll
    for (int mi = 0; mi < 4; ++mi)
#pragma unroll
        for (int nj = 0; nj < 4; ++nj) acc[mi][nj] = (f32x4){0.f, 0.f, 0.f, 0.f};

    int4 ra[3][4], rb[3][4];
#define LOADF(S, T)                                                           \
    {                                                                         \
        _Pragma("unroll")                                                     \
        for (int mi = 0; mi < 4; ++mi) {                                      \
            ra[S][mi] = *reinterpret_cast<const int4*>(aB + ((size_t)mi * 24 + (T)) * 512); \
            rb[S][mi] = *reinterpret_cast<const int4*>(bB + ((size_t)mi * 24 + (T)) * 512); \
        }                                                                     \
    }
#define COMPUTEF(S)                                                           \
    {                                                                         \
        union { int4 i; bf16x8 v; } af[4], bf[4];                             \
        _Pragma("unroll")                                                     \
        for (int mi = 0; mi < 4; ++mi) { af[mi].i = ra[S][mi]; bf[mi].i = rb[S][mi]; } \
        __builtin_amdgcn_s_setprio(1);                                        \
        _Pragma("unroll")                                                     \
        for (int mi = 0; mi < 4; ++mi)                                        \
            _Pragma("unroll")                                                 \
            for (int nj = 0; nj < 4; ++nj)                                    \
                acc[mi][nj] = __builtin_amdgcn_mfma_f32_16x16x32_bf16(af[mi].v, bf[nj].v, acc[mi][nj], 0, 0, 0); \
        __builtin_amdgcn_s_setprio(0);                                        \
    }

    LOADF(0, 0);
    LOADF(1, 1);
    LOADF(2, 2);
#pragma unroll
    for (int t = 0; t < 24; ++t) {
        COMPUTEF(t % 3);
        if (t + 3 < 24) { LOADF(t % 3, t + 3); }
    }
#undef LOADF
#undef COMPUTEF

    const int which = col0 / 768;
    const int cb = col0 - which * 768;
#pragma unroll
    for (int mi = 0; mi < 4; ++mi) {
#pragma unroll
        for (int i = 0; i < 4; ++i) {
            int r = row0 + wm * 64 + mi * 16 + lk * 4 + i;
            int b = r >> 10, n = r & 1023;
#pragma unroll
            for (int nj = 0; nj < 4; ++nj) {
                int cw = cb + wn * 64 + nj * 16 + lr;
                int h = cw >> 6, d = cw & 63;
                int bh = b * 12 + h;
                float val = acc[mi][nj][i];
                if (which == 2) {
                    size_t off = ((((size_t)bh * 16 + (n >> 6)) * 4 + ((n >> 4) & 3)) * 2 + ((n >> 3) & 1)) * 512
                                 + d * 8 + (n & 7);
                    Vf[off] = f2bf(val);
                } else {
                    size_t off = ((((size_t)bh * 32 + (n >> 5)) * 4 + (d >> 4)) * 2 + ((d >> 3) & 1)) * 256
                                 + (n & 31) * 8 + (d & 7);
                    if (which == 0) Qf[off] = f2bf(val * 0.18033688f);   // 0.125*log2(e)
                    else            Kf[off] = f2bf(val);
                }
            }
        }
    }
}

// ---------------------------------------------------------------------------
// Flash attention (unchanged except: final store writes fragment-order attnF).
// ---------------------------------------------------------------------------
#define GETO(dt, r) ((dt) == 0 ? o0[r] : o1[r])

__global__ __launch_bounds__(256) void attn_mfma(const u16* __restrict__ Qf,
                                                 const u16* __restrict__ Kf,
                                                 const u16* __restrict__ Vf,
                                                 u16* __restrict__ attnF) {
    __shared__ float OtM[2][64][33];
    __shared__ float Lm[2][32], Ll[2][32];
    __shared__ u16 Os[2][32][72];

    const int tid = threadIdx.x;
    const int lane = tid & 63;
    const int w = tid >> 6;
    const int qsub = w & 1;
    const int half = w >> 1;
    const int l31 = lane & 31;
    const int hi = lane >> 5;

    const int bid = blockIdx.x;
    const int lin = (bid & 7) * 96 + (bid >> 3);
    const int qt = lin & 15;
    const int bh = lin >> 4;

    const u16* Qh = Qf + (size_t)bh * 65536;
    const u16* Kh = Kf + (size_t)bh * 65536;
    const u16* Vh = Vf + (size_t)bh * 65536;

    bf16x8 qf[4];
#pragma unroll
    for (int kt = 0; kt < 4; ++kt)
        qf[kt] = *reinterpret_cast<const bf16x8*>(
            Qh + (((size_t)(qt * 2 + qsub) * 4 + kt) * 2 + hi) * 256 + l31 * 8);

    f32x16 o0 = ZERO16, o1 = ZERO16;
    float m = -1e30f, l = 0.f;

    for (int it = 0; it < 8; ++it) {
        const int kb0 = it * 4 + half * 2;
        const int kvb = it * 2 + half;

        bf16x8 kf0[4], kf1[4];
#pragma unroll
        for (int kt = 0; kt < 4; ++kt) {
            kf0[kt] = *reinterpret_cast<const bf16x8*>(
                Kh + (((size_t)kb0 * 4 + kt) * 2 + hi) * 256 + l31 * 8);
            kf1[kt] = *reinterpret_cast<const bf16x8*>(
                Kh + (((size_t)(kb0 + 1) * 4 + kt) * 2 + hi) * 256 + l31 * 8);
        }
        bf16x8 vf0[4], vf1[4];
#pragma unroll
        for (int ks = 0; ks < 4; ++ks) {
            const u16* vb = Vh + (((size_t)kvb * 4 + ks) * 2 + hi) * 512;
            vf0[ks] = *reinterpret_cast<const bf16x8*>(vb + l31 * 8);
            vf1[ks] = *reinterpret_cast<const bf16x8*>(vb + (l31 + 32) * 8);
        }

        f32x16 s0 = ZERO16, s1 = ZERO16;
        __builtin_amdgcn_s_setprio(1);
#pragma unroll
        for (int kt = 0; kt < 4; ++kt) s0 = __builtin_amdgcn_mfma_f32_32x32x16_bf16(kf0[kt], qf[kt], s0, 0, 0, 0);
#pragma unroll
        for (int kt = 0; kt < 4; ++kt) s1 = __builtin_amdgcn_mfma_f32_32x32x16_bf16(kf1[kt], qf[kt], s1, 0, 0, 0);
        __builtin_amdgcn_s_setprio(0);

        float mx[8];
#pragma unroll
        for (int i = 0; i < 8; ++i)
            mx[i] = fmaxf(fmaxf(s0[2*i], s0[2*i+1]), fmaxf(s1[2*i], s1[2*i+1]));
        float pmax = fmaxf(fmaxf(fmaxf(mx[0], mx[1]), fmaxf(mx[2], mx[3])),
                           fmaxf(fmaxf(mx[4], mx[5]), fmaxf(mx[6], mx[7])));
        pmax = xhalf_max(pmax);

        if (!__all(pmax <= m + 8.f)) {
            float mn = fmaxf(m, pmax);
            float c = __builtin_amdgcn_exp2f(m - mn);
            m = mn; l *= c;
            o0 = o0 * c; o1 = o1 * c;
        }

#pragma unroll
        for (int r = 0; r < 16; ++r) s0[r] = __builtin_amdgcn_exp2f(s0[r] - m);
#pragma unroll
        for (int r = 0; r < 16; ++r) s1[r] = __builtin_amdgcn_exp2f(s1[r] - m);
        float sm[8];
#pragma unroll
        for (int i = 0; i < 8; ++i)
            sm[i] = (s0[2*i] + s0[2*i+1]) + (s1[2*i] + s1[2*i+1]);
        float tsum = ((sm[0]+sm[1]) + (sm[2]+sm[3])) + ((sm[4]+sm[5]) + (sm[6]+sm[7]));
        l += xhalf_sum(tsum);

        bf16x8 pb[4];
#define PACK_GROUP(S, G, OUT)                                           \
        {                                                               \
            u32 X0 = cvtpk(S[8*(G)+0], S[8*(G)+1]);                     \
            u32 X1 = cvtpk(S[8*(G)+2], S[8*(G)+3]);                     \
            u32 Y0 = cvtpk(S[8*(G)+4], S[8*(G)+5]);                     \
            u32 Y1 = cvtpk(S[8*(G)+6], S[8*(G)+7]);                     \
            u32 X0s = (u32)__shfl_xor((int)X0, 32);                     \
            u32 X1s = (u32)__shfl_xor((int)X1, 32);                     \
            u32 Y0s = (u32)__shfl_xor((int)Y0, 32);                     \
            u32 Y1s = (u32)__shfl_xor((int)Y1, 32);                     \
            union { u32 u[4]; bf16x8 v; } pk_;                          \
            pk_.u[0] = hi ? Y0s : X0;                                   \
            pk_.u[1] = hi ? Y1s : X1;                                   \
            pk_.u[2] = hi ? Y0 : X0s;                                   \
            pk_.u[3] = hi ? Y1 : X1s;                                   \
            OUT = pk_.v;                                                \
        }
        PACK_GROUP(s0, 0, pb[0]);
        PACK_GROUP(s0, 1, pb[1]);
        PACK_GROUP(s1, 0, pb[2]);
        PACK_GROUP(s1, 1, pb[3]);
#undef PACK_GROUP

        __builtin_amdgcn_s_setprio(1);
#pragma unroll
        for (int ks = 0; ks < 4; ++ks) {
            o0 = __builtin_amdgcn_mfma_f32_32x32x16_bf16(vf0[ks], pb[ks], o0, 0, 0, 0);
            o1 = __builtin_amdgcn_mfma_f32_32x32x16_bf16(vf1[ks], pb[ks], o1, 0, 0, 0);
        }
        __builtin_amdgcn_s_setprio(0);
    }

    if (half == 1) {
#pragma unroll
        for (int dt = 0; dt < 2; ++dt)
#pragma unroll
            for (int r = 0; r < 16; ++r)
                OtM[qsub][dt * 32 + (r & 3) + 8 * (r >> 2) + 4 * hi][l31] = GETO(dt, r);
        Lm[qsub][l31] = m;
        Ll[qsub][l31] = l;
    }
    __syncthreads();
    if (half == 0) {
        float m2 = Lm[qsub][l31], l2 = Ll[qsub][l31];
        float mn = fmaxf(m, m2);
        float a = __builtin_amdgcn_exp2f(m - mn);
        float bsc = __builtin_amdgcn_exp2f(m2 - mn);
        float lm = l * a + l2 * bsc;
        float inv = 1.0f / lm;
        float av = a * inv, bv = bsc * inv;
#pragma unroll
        for (int dt = 0; dt < 2; ++dt)
#pragma unroll
            for (int rq = 0; rq < 4; ++rq) {
                int d0 = dt * 32 + 8 * rq + 4 * hi;
                float v0 = GETO(dt, rq * 4 + 0) * av + OtM[qsub][d0 + 0][l31] * bv;
                float v1 = GETO(dt, rq * 4 + 1) * av + OtM[qsub][d0 + 1][l31] * bv;
                float v2 = GETO(dt, rq * 4 + 2) * av + OtM[qsub][d0 + 2][l31] * bv;
                float v3 = GETO(dt, rq * 4 + 3) * av + OtM[qsub][d0 + 3][l31] * bv;
                uint2 pr;
                pr.x = cvtpk(v0, v1);
                pr.y = cvtpk(v2, v3);
                *reinterpret_cast<uint2*>(&Os[qsub][l31][d0]) = pr;
            }
    }
    __syncthreads();

    // write-out to FRAGMENT-ORDER attnF (feeds zero-LDS gemm_out)
    const int b = bh / 12, h = bh % 12;
#pragma unroll
    for (int it2 = 0; it2 < 2; ++it2) {
        int idx = tid + it2 * 256;
        int token = idx >> 3;
        int chunk = idx & 7;
        int4 v = *reinterpret_cast<const int4*>(&Os[token >> 5][token & 31][chunk * 8]);
        int mm = b * 1024 + qt * 64 + token;
        int kk = h * 64 + chunk * 8;
        *reinterpret_cast<int4*>(attnF + fragoff(mm, kk)) = v;
    }
}

// ---------------------------------------------------------------------------
// GEMM2: out = attnF @ wO + b_out (both fragment-order).  Same zero-LDS
// structure.  192 blocks = 8 XCD x (4 row x 6 col).
// ---------------------------------------------------------------------------
__global__ __launch_bounds__(256) void gemm_out(const u16* __restrict__ attnF,
                                                const u16* __restrict__ wO,
                                                const float* __restrict__ bias,
                                                float* __restrict__ out) {
    const int tid = threadIdx.x;
    const int lane = tid & 63;
    const int w = tid >> 6;
    const int wm = w >> 1, wn = w & 1;
    const int lr = lane & 15;
    const int lk = lane >> 4;
    const int xcd = blockIdx.x & 7;
    const int lid = blockIdx.x >> 3;                  // 0..23
    const int row0 = (xcd * 4 + (lid & 3)) * 128;
    const int col0 = (lid >> 2) * 128;
    const int R0 = row0 + wm * 64;
    const int C0 = col0 + wn * 64;
    const u16* aB = attnF + (size_t)(R0 >> 4) * 24 * 512 + lane * 8;
    const u16* bB = wO + (size_t)(C0 >> 4) * 24 * 512 + lane * 8;

    f32x4 acc[4][4];
#pragma unroll
    for (int mi = 0; mi < 4; ++mi)
#pragma unroll
        for (int nj = 0; nj < 4; ++nj) acc[mi][nj] = (f32x4){0.f, 0.f, 0.f, 0.f};

    int4 ra[3][4], rb[3][4];
#define LOADF(S, T)                                                           \
    {                                                                         \
        _Pragma("unroll")                                                     \
        for (int mi = 0; mi < 4; ++mi) {                                      \
            ra[S][mi] = *reinterpret_cast<const int4*>(aB + ((size_t)mi * 24 + (T)) * 512); \
            rb[S][mi] = *reinterpret_cast<const int4*>(bB + ((size_t)mi * 24 + (T)) * 512); \
        }                                                                     \
    }
#define COMPUTEF(S)                                                           \
    {                                                                         \
        union { int4 i; bf16x8 v; } af[4], bf[4];                             \
        _Pragma("unroll")                                                     \
        for (int mi = 0; mi < 4; ++mi) { af[mi].i = ra[S][mi]; bf[mi].i = rb[S][mi]; } \
        __builtin_amdgcn_s_setprio(1);                                        \
        _Pragma("unroll")                                                     \
        for (int mi = 0; mi < 4; ++mi)                                        \
            _Pragma("unroll")                                                 \
            for (int nj = 0; nj < 4; ++nj)                                    \
                acc[mi][nj] = __builtin_amdgcn_mfma_f32_16x16x32_bf16(af[mi].v, bf[nj].v, acc[mi][nj], 0, 0, 0); \
        __builtin_amdgcn_s_setprio(0);                                        \
    }

    LOADF(0, 0);
    LOADF(1, 1);
    LOADF(2, 2);
#pragma unroll
    for (int t = 0; t < 24; ++t) {
        COMPUTEF(t % 3);
        if (t + 3 < 24) { LOADF(t % 3, t + 3); }
    }
#undef LOADF
#undef COMPUTEF

#pragma unroll
    for (int mi = 0; mi < 4; ++mi)
#pragma unroll
        for (int i = 0; i < 4; ++i) {
            int r = row0 + wm * 64 + mi * 16 + lk * 4 + i;
#pragma unroll
            for (int nj = 0; nj < 4; ++nj) {
                int c = col0 + wn * 64 + nj * 16 + lr;
                out[(size_t)r * 768 + c] = acc[mi][nj][i] + bias[c];
            }
        }
}

// ---------------------------------------------------------------------------
extern "C" void kernel_launch(void* const* d_in, const int* in_sizes, int n_in,
                              void* d_out, int out_size, void* d_ws, size_t ws_size,
                              hipStream_t stream) {
    const float* x     = (const float*)d_in[0];
    const float* w_qkv = (const float*)d_in[1];
    const float* w_out = (const float*)d_in[2];
    const float* b_out = (const float*)d_in[3];
    float* out = (float*)d_out;

    u16* ws = (u16*)d_ws;
    const size_t n_x = (size_t)4096 * 768;
    u16* xA     = ws;                             // frag-order [4096][768]
    u16* wB     = xA + n_x;                       // frag-order [2304][768]
    u16* wO     = wB + (size_t)2304 * 768;        // frag-order [768][768]
    u16* Qfr    = wO + (size_t)768 * 768;         // attn fragment-order, 65536/bh
    u16* Kfr    = Qfr + n_x;
    u16* Vfr    = Kfr + n_x;
    u16* attnF  = Vfr + n_x;                      // frag-order [4096][768]

    prep<<<3840, 256, 0, stream>>>(x, w_qkv, w_out, xA, wB, wO);
    gemm_qkv<<<576, 256, 0, stream>>>(xA, wB, Qfr, Kfr, Vfr);
    attn_mfma<<<768, 256, 0, stream>>>(Qfr, Kfr, Vfr, attnF);
    gemm_out<<<192, 256, 0, stream>>>(attnF, wO, b_out, out);
}